// Round 1
// baseline (775.524 us; speedup 1.0000x reference)
//
#include <hip/hip_runtime.h>
#include <hip/hip_bf16.h>

#define DIM 128
#define NBLK 8
#define BS 16

// ---------------------------------------------------------------------------
// node_keep_mask dtype detection. JAX bool arrays may be shipped as int32,
// uint8, bf16 (0x3F80), or f32 (0x3F800000). Distinguish by byte patterns of
// the first 512 bytes (values are only 0/1-ish; ~90% ones).
//   mode 0 = int32, 1 = uint8, 2 = uint16/bf16, 3 = float32
// ---------------------------------------------------------------------------
__global__ void detect_mask_kernel(const unsigned char* __restrict__ m,
                                   int* __restrict__ mode_out) {
    if (threadIdx.x != 0 || blockIdx.x != 0) return;
    bool f3f_pos1 = false;   // 0x3F at byte pos ≡ 1 (mod 4)  -> bf16
    bool f3f      = false;   // any 0x3F                      -> bf16 or f32
    bool odd_nz   = false;   // nonzero at odd byte positions -> u8 (or bf16/f32)
    for (int i = 0; i < 512; ++i) {
        unsigned char b = m[i];
        if (b == 0x3F) { f3f = true; if ((i & 3) == 1) f3f_pos1 = true; }
        if ((i & 1) == 1 && b != 0) odd_nz = true;
    }
    int mode;
    if (f3f_pos1)      mode = 2;   // bf16: 0x3F at pos 1 mod 4 (even elements)
    else if (f3f)      mode = 3;   // f32: 0x3F only at pos 3 mod 4
    else if (odd_nz)   mode = 1;   // u8: odd-position bytes carry values
    else               mode = 0;   // i32: only pos ≡ 0 mod 4 nonzero
    *mode_out = mode;
}

__device__ __forceinline__ bool mask_keep(const void* mask, int n, int mode) {
    switch (mode) {
        case 0:  return ((const int*)mask)[n] != 0;
        case 1:  return ((const unsigned char*)mask)[n] != 0;
        case 2:  return ((const unsigned short*)mask)[n] != 0;
        default: return ((const float*)mask)[n] != 0.0f;
    }
}

__device__ __forceinline__ void atomAddF(float* p, float v) {
    // HW global_atomic_add_f32 on gfx90a+ regardless of -munsafe-fp-atomics.
    unsafeAtomicAdd(p, v);
}

// ---------------------------------------------------------------------------
// Kernel A: out[n] = keep[n] ? xb[n] @ blocks[8] : 0   (also initializes out,
// since d_out is poisoned before every launch). 2 nodes per 256-thread block.
// ---------------------------------------------------------------------------
__launch_bounds__(256)
__global__ void self_kernel(const float* __restrict__ x,
                            const float* __restrict__ blocks,
                            const void* __restrict__ mask,
                            const int* __restrict__ mode_p,
                            float* __restrict__ out,
                            int n_nodes) {
    __shared__ float xs[2][DIM];
    const int mode  = *mode_p;
    const int local = threadIdx.x >> 7;        // 0..1: which node in block
    const int d     = threadIdx.x & (DIM - 1); // output element
    const int n     = blockIdx.x * 2 + local;
    const bool ok   = (n < n_nodes);
    if (ok) xs[local][d] = x[n * DIM + d];
    __syncthreads();
    if (!ok) return;

    const int b = d >> 4, j = d & (BS - 1);
    const float* __restrict__ B  = blocks + (8 * NBLK + b) * (BS * BS) + j; // blocks[8][b][i][j]
    const float* __restrict__ xr = &xs[local][b * BS];
    float acc = 0.0f;
    #pragma unroll
    for (int i = 0; i < BS; ++i) acc += xr[i] * B[i * BS];

    out[n * DIM + d] = mask_keep(mask, n, mode) ? acc : 0.0f;
}

// ---------------------------------------------------------------------------
// Kernel B: per edge e with (s, t, r, w):
//   out[t][d] += w * sum_i x[s][b*16+i] * blocks[r][b][i][j]
//   out[s][d] += w * sum_i x[t][b*16+i] * blocks[r][b][i][j]
// 2 edges per 256-thread block; x rows staged in LDS; B row loads are shared
// between fwd and bwd messages (16 loads, 32 FMAs, 2 atomics per thread).
// ---------------------------------------------------------------------------
__launch_bounds__(256)
__global__ void edge_kernel(const float* __restrict__ x,
                            const float* __restrict__ blocks,
                            const int* __restrict__ source,
                            const int* __restrict__ target,
                            const int* __restrict__ etype,
                            const float* __restrict__ ew,
                            float* __restrict__ out,
                            int n_edges) {
    __shared__ float sx[2][2][DIM];            // [local edge][src/tgt][DIM]
    const int local = threadIdx.x >> 7;
    const int d     = threadIdx.x & (DIM - 1);
    const int e     = blockIdx.x * 2 + local;
    const bool ok   = (e < n_edges);

    int s = 0, t = 0, r = 0;
    float w = 0.0f;
    if (ok) {
        s = source[e]; t = target[e]; r = etype[e]; w = ew[e];
        sx[local][0][d] = x[s * DIM + d];
        sx[local][1][d] = x[t * DIM + d];
    }
    __syncthreads();
    if (!ok) return;

    const int b = d >> 4, j = d & (BS - 1);
    const float* __restrict__ B   = blocks + (r * NBLK + b) * (BS * BS) + j;
    const float* __restrict__ xsr = &sx[local][0][b * BS];
    const float* __restrict__ xtr = &sx[local][1][b * BS];

    float af = 0.0f, ab = 0.0f;
    #pragma unroll
    for (int i = 0; i < BS; ++i) {
        const float bw = B[i * BS];            // shared between fwd & bwd
        af += xsr[i] * bw;
        ab += xtr[i] * bw;
    }
    atomAddF(&out[t * DIM + d], af * w);
    atomAddF(&out[s * DIM + d], ab * w);
}

// ---------------------------------------------------------------------------
extern "C" void kernel_launch(void* const* d_in, const int* in_sizes, int n_in,
                              void* d_out, int out_size, void* d_ws, size_t ws_size,
                              hipStream_t stream) {
    const float* x      = (const float*)d_in[0];
    const float* blocks = (const float*)d_in[1];
    const void*  mask   = d_in[2];
    const int*   source = (const int*)d_in[3];
    const int*   target = (const int*)d_in[4];
    const int*   etype  = (const int*)d_in[5];
    const float* ew     = (const float*)d_in[6];
    float*       out    = (float*)d_out;

    const int n_nodes = in_sizes[0] / DIM;
    const int n_edges = in_sizes[3];
    int* mode = (int*)d_ws;

    hipLaunchKernelGGL(detect_mask_kernel, dim3(1), dim3(64), 0, stream,
                       (const unsigned char*)mask, mode);
    hipLaunchKernelGGL(self_kernel, dim3((n_nodes + 1) / 2), dim3(256), 0, stream,
                       x, blocks, mask, mode, out, n_nodes);
    hipLaunchKernelGGL(edge_kernel, dim3((n_edges + 1) / 2), dim3(256), 0, stream,
                       x, blocks, source, target, etype, ew, out, n_edges);
}